// Round 1
// 6655.508 us; speedup vs baseline: 1.4451x; 1.4451x over previous
//
#include <hip/hip_runtime.h>

#define DT 0.01f
#define NH 512
#define T_STEPS 1024
#define NB 128
#define SLICE 64
#define SCALE_F 4194304.0f                 // 2^22 fixed-point scale for partial-rec exchange
#define INV_SCALE 2.384185791015625e-07f   // 1 / 2^22

typedef _Float16 h2v __attribute__((ext_vector_type(2)));
typedef _Float16 h8v __attribute__((ext_vector_type(8)));

#if defined(__has_builtin)
#if __has_builtin(__builtin_amdgcn_fdot2)
#define HAVE_FDOT2 1
#endif
#endif

#ifdef HAVE_FDOT2
#define FDOT2(a, b, c) __builtin_amdgcn_fdot2((a), (b), (c), false)
#else
static __device__ __forceinline__ float FDOT2(h2v a, h2v b, float c) {
    return c + (float)a[0] * (float)b[0] + (float)a[1] * (float)b[1];
}
#endif

// LDS layout (bytes)
#define O_W1 0        // [64 i8][64 jj] h8v = 64 KB   w1p: w[i8*8+e][jm+jj]   (col-slice, col-major)
#define O_W2 65536    // [512 p][8 k^sw] h8v = 64 KB  w2p: w[p][jm+k*8+e]     (col-slice, row-major, XOR-swizzled)
#define O_HY 131072   // [4 r][512 i] fp16 = 4 KB     full hy (redundant per member)
#define O_S  135168   // [4 r][64 jj] fp16 = 512 B    own s slice
#define O_Z  135680   // [8 q][64 jj][4 r] f32 = 8 KB pass-1 octant partials
#define LDS_BYTES 143872

// ---------- kernel 1: i2h = tanh(x @ x2h) -> written into d_out all_states slots ----------
__global__ __launch_bounds__(512) void i2h_kernel(const float* __restrict__ x,
                                                  const float* __restrict__ x2h,
                                                  float* __restrict__ out) {
    __shared__ __align__(16) float xs[16 * 64];
    int bt0 = blockIdx.x * 16;
    int tid = threadIdx.x;
    xs[tid]       = x[(size_t)bt0 * 64 + tid];
    xs[tid + 512] = x[(size_t)bt0 * 64 + tid + 512];
    __syncthreads();

    float acc[16];
    #pragma unroll
    for (int r = 0; r < 16; ++r) acc[r] = 0.f;

    for (int i4 = 0; i4 < 16; ++i4) {
        float w0 = x2h[(i4 * 4 + 0) * 512 + tid];
        float w1 = x2h[(i4 * 4 + 1) * 512 + tid];
        float w2 = x2h[(i4 * 4 + 2) * 512 + tid];
        float w3 = x2h[(i4 * 4 + 3) * 512 + tid];
        #pragma unroll
        for (int r = 0; r < 16; ++r) {
            float4 xv = *(const float4*)&xs[r * 64 + i4 * 4];
            acc[r] += xv.x * w0 + xv.y * w1 + xv.z * w2 + xv.w * w3;
        }
    }
    #pragma unroll
    for (int r = 0; r < 16; ++r)
        out[(size_t)(bt0 + r) * 512 + tid] = tanhf(acc[r]);
}

// ---------- kernel 2: recurrence. 32 groups x 8 members; ONE global exchange per step.
// Member m owns column-slice [jm, jm+64). Pass 1: s-slice locally from full hy (no exchange).
// Pass 2: partial rec for ALL 512 outputs from own j-slice; reduced across members via
// fixed-point integer atomics (diff-trick, double-buffered). Every member then redundantly
// computes the identical full hy/hz update -> no hy exchange. ----------
__global__ __launch_bounds__(512, 1) void recur3(const float* __restrict__ h2h,
                                                 const float* __restrict__ bias,
                                                 float* __restrict__ out,
                                                 int* __restrict__ recbuf,
                                                 unsigned int* __restrict__ flags) {
    extern __shared__ unsigned char lds[];
    h8v* w1p      = (h8v*)(lds + O_W1);
    h8v* w2p      = (h8v*)(lds + O_W2);
    _Float16* hyH = (_Float16*)(lds + O_HY);
    _Float16* stg = (_Float16*)(lds + O_S);
    float* zred   = (float*)(lds + O_Z);

    const int tid = threadIdx.x;
    const int G   = blockIdx.x >> 3;   // group (4 batch rows)
    const int m   = blockIdx.x & 7;    // member (64-col slice)
    const int jj  = tid & 63;
    const int q   = tid >> 6;          // octant / wave id (pass 1)
    const int jm  = m * SLICE;
    const int p   = tid;               // pass-2 / state column (0..511)

    // ---- one-time: load + fp16-convert weight col-slice into LDS, two layouts ----
    for (int it = 0; it < 8; ++it) {
        int gidx = it * 512 + tid;
        int i8 = gidx >> 6, j = gidx & 63;          // lanes run over j -> coalesced
        h8v wv;
        #pragma unroll
        for (int e = 0; e < 8; ++e)
            wv[e] = (_Float16)h2h[(size_t)(i8 * 8 + e) * NH + jm + j];
        w1p[i8 * 64 + j] = wv;
    }
    for (int it = 0; it < 8; ++it) {
        int gidx = it * 512 + tid;
        int pr = gidx >> 3, k = gidx & 7;           // lanes run over k,e -> coalesced
        const float* rp = h2h + (size_t)pr * NH + jm + k * 8;
        h8v wv;
        #pragma unroll
        for (int e = 0; e < 8; ++e) wv[e] = (_Float16)rp[e];
        w2p[pr * 8 + (k ^ (pr & 7))] = wv;          // XOR swizzle: conflict-free row reads
    }

    // zero hy for t=0
    #pragma unroll
    for (int r = 0; r < 4; ++r) hyH[r * NH + p] = (_Float16)0.f;

    int* rbA = recbuf + G * 4096;      // even-t accumulator (2048 ints)
    int* rbB = rbA + 2048;             // odd-t accumulator
    unsigned int* flagBase = flags + G * 256;   // 8 members x 32 uints (128 B pad)
    unsigned int* myflag   = flagBase + m * 32;

    const float bj = bias[jm + jj];

    const float* ivBase = out + (size_t)(4 * G) * T_STEPS * NH + p;
    float* outBase      = out + (size_t)(4 * G) * T_STEPS * NH + p;
    const bool writer = ((p >> 6) == m);   // this member writes cols [jm, jm+64)

    float hy[4] = {0.f, 0.f, 0.f, 0.f};
    float hz[4] = {0.f, 0.f, 0.f, 0.f};
    int pA[4] = {0, 0, 0, 0};   // prev quantized partials, even buffer
    int pB[4] = {0, 0, 0, 0};   // prev quantized partials, odd buffer

    __syncthreads();   // weights + hyH ready

    for (int t = 0; t < T_STEPS; ++t) {
        // iv prefetch: full 4x512 i2h row (redundant across members; slot not yet
        // overwritten: peers write hy(t) only after barrier(t), which needs our arrival,
        // and our syncthreads-before-flag drains these loads first).
        float iv[4];
        #pragma unroll
        for (int r = 0; r < 4; ++r)
            iv[r] = ivBase[((size_t)r * T_STEPS + t) * NH];

        // ---- pass 1: z[r][jm+jj] octant partials over i in [64q, 64q+64) ----
        {
            float acc[4] = {0.f, 0.f, 0.f, 0.f};
            #pragma unroll
            for (int k = 0; k < 8; ++k) {
                const int i8 = q * 8 + k;
                h8v wv = w1p[i8 * 64 + jj];
                h2v wA = {wv[0], wv[1]}, wB = {wv[2], wv[3]},
                    wC = {wv[4], wv[5]}, wD = {wv[6], wv[7]};
                #pragma unroll
                for (int rr = 0; rr < 4; ++rr) {
                    h8v av = *(const h8v*)(hyH + rr * NH + i8 * 8);
                    h2v aA = {av[0], av[1]}, aB = {av[2], av[3]},
                        aC = {av[4], av[5]}, aD = {av[6], av[7]};
                    float a = acc[rr];
                    a = FDOT2(wA, aA, a); a = FDOT2(wB, aB, a);
                    a = FDOT2(wC, aC, a); a = FDOT2(wD, aD, a);
                    acc[rr] = a;
                }
            }
            *(float4*)(zred + (q * 64 + jj) * 4) = make_float4(acc[0], acc[1], acc[2], acc[3]);
        }
        __syncthreads();

        // owner: 8-way reduce + bias + tanh -> s slice (stays local!)
        if (q < 4) {
            float z = bj;
            #pragma unroll
            for (int qq = 0; qq < 8; ++qq) z += zred[(qq * 64 + jj) * 4 + q];
            stg[q * 64 + jj] = (_Float16)tanhf(z);
        }
        __syncthreads();

        // ---- pass 2: partial rec[r][p] over own j-slice, for ALL 512 p ----
        float acc[4] = {0.f, 0.f, 0.f, 0.f};
        {
            const int sw = p & 7;
            #pragma unroll
            for (int k = 0; k < 8; ++k) {
                h8v wv = w2p[p * 8 + (k ^ sw)];
                h2v wA = {wv[0], wv[1]}, wB = {wv[2], wv[3]},
                    wC = {wv[4], wv[5]}, wD = {wv[6], wv[7]};
                #pragma unroll
                for (int r = 0; r < 4; ++r) {
                    h8v sv = *(const h8v*)(stg + r * 64 + k * 8);
                    h2v sA = {sv[0], sv[1]}, sB = {sv[2], sv[3]},
                        sC = {sv[4], sv[5]}, sD = {sv[6], sv[7]};
                    float a = acc[r];
                    a = FDOT2(wA, sA, a); a = FDOT2(wB, sB, a);
                    a = FDOT2(wC, sC, a); a = FDOT2(wD, sD, a);
                    acc[r] = a;
                }
            }
        }

        // ---- fixed-point atomic diff-add into the parity buffer (no zeroing needed) ----
        int* rb = (t & 1) ? rbB : rbA;
        const bool odd = (t & 1);
        #pragma unroll
        for (int r = 0; r < 4; ++r) {
            int qv = (int)(acc[r] * SCALE_F);
            int d;
            if (odd) { d = qv - pB[r]; pB[r] = qv; }
            else     { d = qv - pA[r]; pA[r] = qv; }
            __hip_atomic_fetch_add(rb + r * NH + p, d,
                                   __ATOMIC_RELAXED, __HIP_MEMORY_SCOPE_AGENT);
        }

        // ---- single barrier: per-member release flags, 8-lane parallel poll ----
        __syncthreads();   // drains vmcnt: all atomic adds (and iv loads) complete
        if (tid == 0)
            __hip_atomic_store(myflag, (unsigned int)(t + 1),
                               __ATOMIC_RELEASE, __HIP_MEMORY_SCOPE_AGENT);
        if (tid < 8) {
            const unsigned int* fp = flagBase + tid * 32;
            while (__hip_atomic_load(fp, __ATOMIC_RELAXED, __HIP_MEMORY_SCOPE_AGENT)
                   <= (unsigned int)t)
                __builtin_amdgcn_s_sleep(1);
        }
        __syncthreads();

        // ---- read reduced rec; everyone does the identical full update ----
        int sums[4];
        #pragma unroll
        for (int r = 0; r < 4; ++r)
            sums[r] = __hip_atomic_load(rb + r * NH + p,
                                        __ATOMIC_RELAXED, __HIP_MEMORY_SCOPE_AGENT);
        #pragma unroll
        for (int r = 0; r < 4; ++r) {
            float rec = (float)sums[r] * INV_SCALE;
            hz[r] = hz[r] + DT * (iv[r] - rec - hy[r] - hz[r]);
            hy[r] = hy[r] + DT * hz[r];
            hyH[r * NH + p] = (_Float16)hy[r];
        }
        if (writer) {
            #pragma unroll
            for (int r = 0; r < 4; ++r)
                outBase[((size_t)r * T_STEPS + t) * NH] = hy[r];
        }
        __syncthreads();   // hyH ready for next pass 1
    }

    // hy_f (concatenated after all_states)
    if (writer) {
        #pragma unroll
        for (int r = 0; r < 4; ++r)
            out[(size_t)NB * T_STEPS * NH + (size_t)(4 * G + r) * NH + p] = hy[r];
    }
}

// ---------- launch ----------
extern "C" void kernel_launch(void* const* d_in, const int* in_sizes, int n_in,
                              void* d_out, int out_size, void* d_ws, size_t ws_size,
                              hipStream_t stream) {
    const float* x    = (const float*)d_in[0];   // [128,1024,64]
    const float* x2h  = (const float*)d_in[1];   // [64,512]
    const float* h2h  = (const float*)d_in[2];   // [512,512]
    const float* bias = (const float*)d_in[3];   // [512]
    float* out = (float*)d_out;

    // ws layout: flags 32 KB | recbuf 512 KB (32 groups x 2 bufs x 2048 int)
    unsigned int* flags = (unsigned int*)d_ws;
    int* recbuf         = (int*)((char*)d_ws + 32768);

    hipMemsetAsync(d_ws, 0, 32768 + 524288, stream);

    i2h_kernel<<<8192, 512, 0, stream>>>(x, x2h, out);

    hipFuncSetAttribute((const void*)recur3,
                        hipFuncAttributeMaxDynamicSharedMemorySize, LDS_BYTES);
    recur3<<<256, 512, LDS_BYTES, stream>>>(h2h, bias, out, recbuf, flags);
}

// Round 2
// 5028.322 us; speedup vs baseline: 1.9128x; 1.3236x over previous
//
#include <hip/hip_runtime.h>

#define DT 0.01f
#define NH 512
#define T_STEPS 1024
#define NB 128
#define SLICE 64
#define SCALE_F 262144.0f              // 2^18 fixed-point scale
#define INV_SCALE 3.814697265625e-6f   // 2^-18

typedef _Float16 h2v __attribute__((ext_vector_type(2)));
typedef _Float16 h8v __attribute__((ext_vector_type(8)));

#if defined(__has_builtin)
#if __has_builtin(__builtin_amdgcn_fdot2)
#define HAVE_FDOT2 1
#endif
#endif

#ifdef HAVE_FDOT2
#define FDOT2(a, b, c) __builtin_amdgcn_fdot2((a), (b), (c), false)
#else
static __device__ __forceinline__ float FDOT2(h2v a, h2v b, float c) {
    return c + (float)a[0] * (float)b[0] + (float)a[1] * (float)b[1];
}
#endif

// LDS layout (bytes)
#define O_W1 0        // [64 i8][64 jj] h8v = 64 KB   w1p: w[i8*8+e][jm+jj]   (col-slice, col-major)
#define O_W2 65536    // [512 p][8 k^sw] h8v = 64 KB  w2p: w[p][jm+k*8+e]     (col-slice, row-major, XOR-swizzled)
#define O_HY 131072   // [4 r][512 i] fp16 = 4 KB     full hy (redundant per member)
#define O_S  135168   // [4 r][64 j] fp16 = 512 B     own s slice
#define LDS_BYTES 135680

// ---------- kernel 1: i2h = tanh(x @ x2h) -> written into d_out all_states slots ----------
__global__ __launch_bounds__(512) void i2h_kernel(const float* __restrict__ x,
                                                  const float* __restrict__ x2h,
                                                  float* __restrict__ out) {
    __shared__ __align__(16) float xs[16 * 64];
    int bt0 = blockIdx.x * 16;
    int tid = threadIdx.x;
    xs[tid]       = x[(size_t)bt0 * 64 + tid];
    xs[tid + 512] = x[(size_t)bt0 * 64 + tid + 512];
    __syncthreads();

    float acc[16];
    #pragma unroll
    for (int r = 0; r < 16; ++r) acc[r] = 0.f;

    for (int i4 = 0; i4 < 16; ++i4) {
        float w0 = x2h[(i4 * 4 + 0) * 512 + tid];
        float w1 = x2h[(i4 * 4 + 1) * 512 + tid];
        float w2 = x2h[(i4 * 4 + 2) * 512 + tid];
        float w3 = x2h[(i4 * 4 + 3) * 512 + tid];
        #pragma unroll
        for (int r = 0; r < 16; ++r) {
            float4 xv = *(const float4*)&xs[r * 64 + i4 * 4];
            acc[r] += xv.x * w0 + xv.y * w1 + xv.z * w2 + xv.w * w3;
        }
    }
    #pragma unroll
    for (int r = 0; r < 16; ++r)
        out[(size_t)(bt0 + r) * 512 + tid] = tanhf(acc[r]);
}

// ---------- kernel 2: recurrence. 32 groups x 8 members; ONE round trip per step.
// Exchange: u64 atomic adds carrying (count<<50)+(diffA<<25)+diffB; poll returns data+count
// in a single load. Pass 1 reduce via lane-pair shfl (no LDS round trip). 2 barriers/step. ----------
__global__ __launch_bounds__(512, 1) void recur4(const float* __restrict__ h2h,
                                                 const float* __restrict__ bias,
                                                 float* __restrict__ out,
                                                 unsigned long long* __restrict__ recbuf) {
    extern __shared__ unsigned char lds[];
    h8v* w1p      = (h8v*)(lds + O_W1);
    h8v* w2p      = (h8v*)(lds + O_W2);
    _Float16* hyH = (_Float16*)(lds + O_HY);
    _Float16* stg = (_Float16*)(lds + O_S);

    const int tid = threadIdx.x;
    const int m   = blockIdx.x >> 5;   // member: bid%8 == G%8 for all members -> same XCD L2
    const int G   = blockIdx.x & 31;   // group (4 batch rows)
    const int jm  = m * SLICE;
    const int p   = tid;               // pass-2 / state column (0..511)

    // pass-1 thread mapping: wave w -> row r1, 32-j block; lane pair splits i into halves
    const int w    = tid >> 6;
    const int r1   = w >> 1;
    const int jj1  = (w & 1) * 32 + ((tid & 63) >> 1);
    const int half = tid & 1;

    // ---- one-time: load + fp16-convert weight col-slice into LDS, two layouts ----
    for (int it = 0; it < 8; ++it) {
        int gidx = it * 512 + tid;
        int i8 = gidx >> 6, j = gidx & 63;          // lanes run over j -> coalesced
        h8v wv;
        #pragma unroll
        for (int e = 0; e < 8; ++e)
            wv[e] = (_Float16)h2h[(size_t)(i8 * 8 + e) * NH + jm + j];
        w1p[i8 * 64 + j] = wv;
    }
    for (int it = 0; it < 8; ++it) {
        int gidx = it * 512 + tid;
        int pr = gidx >> 3, k = gidx & 7;           // lanes run over k,e -> coalesced
        const float* rp = h2h + (size_t)pr * NH + jm + k * 8;
        h8v wv;
        #pragma unroll
        for (int e = 0; e < 8; ++e) wv[e] = (_Float16)rp[e];
        w2p[pr * 8 + (k ^ (pr & 7))] = wv;          // XOR swizzle: conflict-free row reads
    }

    // zero hy for t=0
    #pragma unroll
    for (int r = 0; r < 4; ++r) hyH[r * NH + p] = (_Float16)0.f;

    unsigned long long* rb = recbuf + (size_t)G * 2048;  // [2 parity][2 pack][512 p]

    const float bj1 = bias[jm + jj1];

    const float* ivBase = out + (size_t)(4 * G) * T_STEPS * NH + p;
    float* outBase      = out + (size_t)(4 * G) * T_STEPS * NH + p;
    const bool writer = ((p >> 6) == m);   // this member writes cols [jm, jm+64)

    float hy[4] = {0.f, 0.f, 0.f, 0.f};
    float hz[4] = {0.f, 0.f, 0.f, 0.f};
    int pvA[4] = {0, 0, 0, 0};   // prev quantized partials, even parity
    int pvB[4] = {0, 0, 0, 0};   // prev quantized partials, odd parity

    // prologue: iv(0)
    float iv[4];
    #pragma unroll
    for (int r = 0; r < 4; ++r) iv[r] = ivBase[(size_t)r * T_STEPS * NH];

    __syncthreads();   // weights + hyH ready

    for (int t = 0; t < T_STEPS; ++t) {
        // prefetch iv(t+1): slot untouched until end of step t+1 (writer gated by our
        // step-t atomics, drained below before they issue) -> race-free, latency hidden
        float ivn[4] = {0.f, 0.f, 0.f, 0.f};
        if (t + 1 < T_STEPS) {
            #pragma unroll
            for (int r = 0; r < 4; ++r)
                ivn[r] = ivBase[((size_t)r * T_STEPS + (t + 1)) * NH];
        }

        // ---- pass 1: z[r1][jm+jj1], lane-pair i-split + shfl reduce ----
        {
            float acc = 0.f;
            const _Float16* hyRow = hyH + r1 * NH + half * 256;
            const h8v* wBase = w1p + (half * 32) * 64 + jj1;
            #pragma unroll 8
            for (int kk = 0; kk < 32; ++kk) {
                h8v wv = wBase[kk * 64];
                h8v av = *(const h8v*)(hyRow + kk * 8);
                h2v wA = {wv[0], wv[1]}, wB = {wv[2], wv[3]},
                    wC = {wv[4], wv[5]}, wD = {wv[6], wv[7]};
                h2v aA = {av[0], av[1]}, aB = {av[2], av[3]},
                    aC = {av[4], av[5]}, aD = {av[6], av[7]};
                acc = FDOT2(wA, aA, acc); acc = FDOT2(wB, aB, acc);
                acc = FDOT2(wC, aC, acc); acc = FDOT2(wD, aD, acc);
            }
            float tot = acc + __shfl_xor(acc, 1);
            float sv = tanhf(tot + bj1);
            if (half == 0) stg[r1 * 64 + jj1] = (_Float16)sv;
        }
        __syncthreads();   // stg ready

        // ---- pass 2: partial rec[r][p] over own j-slice, for ALL 512 p ----
        float acc[4] = {0.f, 0.f, 0.f, 0.f};
        {
            const int sw = p & 7;
            #pragma unroll
            for (int k = 0; k < 8; ++k) {
                h8v wv = w2p[p * 8 + (k ^ sw)];
                h2v wA = {wv[0], wv[1]}, wB = {wv[2], wv[3]},
                    wC = {wv[4], wv[5]}, wD = {wv[6], wv[7]};
                #pragma unroll
                for (int r = 0; r < 4; ++r) {
                    h8v sv = *(const h8v*)(stg + r * 64 + k * 8);
                    h2v sA = {sv[0], sv[1]}, sB = {sv[2], sv[3]},
                        sC = {sv[4], sv[5]}, sD = {sv[6], sv[7]};
                    float a = acc[r];
                    a = FDOT2(wA, sA, a); a = FDOT2(wB, sB, a);
                    a = FDOT2(wC, sC, a); a = FDOT2(wD, sD, a);
                    acc[r] = a;
                }
            }
        }

        // ---- quantize, diff, pack 2 rows per u64: (1<<50) + (dA<<25) + dB ----
        int q0 = (int)rintf(acc[0] * SCALE_F);
        int q1 = (int)rintf(acc[1] * SCALE_F);
        int q2 = (int)rintf(acc[2] * SCALE_F);
        int q3 = (int)rintf(acc[3] * SCALE_F);
        int dA0, dB0, dA1, dB1;
        if (t & 1) {
            dA0 = q0 - pvB[0]; pvB[0] = q0;  dB0 = q1 - pvB[1]; pvB[1] = q1;
            dA1 = q2 - pvB[2]; pvB[2] = q2;  dB1 = q3 - pvB[3]; pvB[3] = q3;
        } else {
            dA0 = q0 - pvA[0]; pvA[0] = q0;  dB0 = q1 - pvA[1]; pvA[1] = q1;
            dA1 = q2 - pvA[2]; pvA[2] = q2;  dB1 = q3 - pvA[3]; pvA[3] = q3;
        }
        unsigned long long c0 =
            (1ull << 50) + (unsigned long long)(((long long)dA0 << 25) + (long long)dB0);
        unsigned long long c1 =
            (1ull << 50) + (unsigned long long)(((long long)dA1 << 25) + (long long)dB1);

        const int par = t & 1;
        unsigned long long* e0 = rb + par * 1024 + p;
        unsigned long long* e1 = e0 + 512;

        // drain ivn loads (write-after-read fence vs peers' out overwrite), then publish
        asm volatile("s_waitcnt vmcnt(0)" ::: "memory");
        __hip_atomic_fetch_add(e0, c0, __ATOMIC_RELAXED, __HIP_MEMORY_SCOPE_AGENT);
        __hip_atomic_fetch_add(e1, c1, __ATOMIC_RELAXED, __HIP_MEMORY_SCOPE_AGENT);

        // ---- poll: the load IS the barrier and the data ----
        const long long expc = 8ll * (long long)((t >> 1) + 1);
        long long S0 = 0, S1 = 0, S2 = 0, S3 = 0;
        bool d0 = false, d1 = false;
        for (;;) {
            unsigned long long v0 = 0, v1 = 0;
            if (!d0) v0 = __hip_atomic_load(e0, __ATOMIC_RELAXED, __HIP_MEMORY_SCOPE_AGENT);
            if (!d1) v1 = __hip_atomic_load(e1, __ATOMIC_RELAXED, __HIP_MEMORY_SCOPE_AGENT);
            if (!d0) {
                long long sB = ((long long)(v0 << 39)) >> 39;
                unsigned long long v2 = v0 - (unsigned long long)sB;
                long long sA = ((long long)(v2 << 14)) >> 39;
                long long cnt = (long long)((v2 - ((unsigned long long)sA << 25)) >> 50);
                if (cnt >= expc) { S0 = sA; S1 = sB; d0 = true; }
            }
            if (!d1) {
                long long sB = ((long long)(v1 << 39)) >> 39;
                unsigned long long v2 = v1 - (unsigned long long)sB;
                long long sA = ((long long)(v2 << 14)) >> 39;
                long long cnt = (long long)((v2 - ((unsigned long long)sA << 25)) >> 50);
                if (cnt >= expc) { S2 = sA; S3 = sB; d1 = true; }
            }
            if (d0 && d1) break;
            __builtin_amdgcn_s_sleep(2);
        }

        // ---- identical full update on every member ----
        float rec0 = (float)S0 * INV_SCALE;
        float rec1 = (float)S1 * INV_SCALE;
        float rec2 = (float)S2 * INV_SCALE;
        float rec3 = (float)S3 * INV_SCALE;
        float rec[4] = {rec0, rec1, rec2, rec3};
        #pragma unroll
        for (int r = 0; r < 4; ++r) {
            hz[r] = hz[r] + DT * (iv[r] - rec[r] - hy[r] - hz[r]);
            hy[r] = hy[r] + DT * hz[r];
            hyH[r * NH + p] = (_Float16)hy[r];
        }
        if (writer) {
            #pragma unroll
            for (int r = 0; r < 4; ++r)
                outBase[((size_t)r * T_STEPS + t) * NH] = hy[r];
        }
        #pragma unroll
        for (int r = 0; r < 4; ++r) iv[r] = ivn[r];
        __syncthreads();   // hyH ready for next pass 1
    }

    // hy_f (concatenated after all_states)
    if (writer) {
        #pragma unroll
        for (int r = 0; r < 4; ++r)
            out[(size_t)NB * T_STEPS * NH + (size_t)(4 * G + r) * NH + p] = hy[r];
    }
}

// ---------- launch ----------
extern "C" void kernel_launch(void* const* d_in, const int* in_sizes, int n_in,
                              void* d_out, int out_size, void* d_ws, size_t ws_size,
                              hipStream_t stream) {
    const float* x    = (const float*)d_in[0];   // [128,1024,64]
    const float* x2h  = (const float*)d_in[1];   // [64,512]
    const float* h2h  = (const float*)d_in[2];   // [512,512]
    const float* bias = (const float*)d_in[3];   // [512]
    float* out = (float*)d_out;

    // ws layout: recbuf only: 32 groups x 2048 u64 = 512 KB
    unsigned long long* recbuf = (unsigned long long*)d_ws;

    hipMemsetAsync(d_ws, 0, 32 * 2048 * sizeof(unsigned long long), stream);

    i2h_kernel<<<8192, 512, 0, stream>>>(x, x2h, out);

    hipFuncSetAttribute((const void*)recur4,
                        hipFuncAttributeMaxDynamicSharedMemorySize, LDS_BYTES);
    recur4<<<256, 512, LDS_BYTES, stream>>>(h2h, bias, out, recbuf);
}

// Round 3
// 4384.052 us; speedup vs baseline: 2.1939x; 1.1470x over previous
//
#include <hip/hip_runtime.h>

#define DT 0.01f
#define NH 512
#define T_STEPS 1024
#define NB 128
#define SLICE 64
#define SCALE_F 262144.0f              // 2^18 fixed-point scale
#define INV_SCALE 3.814697265625e-6f   // 2^-18

typedef _Float16 h2v __attribute__((ext_vector_type(2)));
typedef _Float16 h8v __attribute__((ext_vector_type(8)));

#if defined(__has_builtin)
#if __has_builtin(__builtin_amdgcn_fdot2)
#define HAVE_FDOT2 1
#endif
#endif

#ifdef HAVE_FDOT2
#define FDOT2(a, b, c) __builtin_amdgcn_fdot2((a), (b), (c), false)
#else
static __device__ __forceinline__ float FDOT2(h2v a, h2v b, float c) {
    return c + (float)a[0] * (float)b[0] + (float)a[1] * (float)b[1];
}
#endif

// LDS layout (bytes)
#define O_W1 0        // [64 i8][64 jj] h8v = 64 KB   w1p: w[i8*8+e][jm+jj]   (col-slice, col-major)
#define O_W2 65536    // [512 p][8 k^sw] h8v = 64 KB  w2p: w[p][jm+k*8+e]     (col-slice, row-major, XOR-swizzled)
#define O_HY 131072   // [4 r][512 i] fp16 = 4 KB     full hy (redundant per member)
#define O_S  135168   // [4 r][64 j] fp16 = 512 B     own s slice
#define LDS_BYTES 135680

// ---------- kernel 1: i2h = tanh(x @ x2h) -> written into d_out all_states slots ----------
__global__ __launch_bounds__(512) void i2h_kernel(const float* __restrict__ x,
                                                  const float* __restrict__ x2h,
                                                  float* __restrict__ out) {
    __shared__ __align__(16) float xs[16 * 64];
    int bt0 = blockIdx.x * 16;
    int tid = threadIdx.x;
    xs[tid]       = x[(size_t)bt0 * 64 + tid];
    xs[tid + 512] = x[(size_t)bt0 * 64 + tid + 512];
    __syncthreads();

    float acc[16];
    #pragma unroll
    for (int r = 0; r < 16; ++r) acc[r] = 0.f;

    for (int i4 = 0; i4 < 16; ++i4) {
        float w0 = x2h[(i4 * 4 + 0) * 512 + tid];
        float w1 = x2h[(i4 * 4 + 1) * 512 + tid];
        float w2 = x2h[(i4 * 4 + 2) * 512 + tid];
        float w3 = x2h[(i4 * 4 + 3) * 512 + tid];
        #pragma unroll
        for (int r = 0; r < 16; ++r) {
            float4 xv = *(const float4*)&xs[r * 64 + i4 * 4];
            acc[r] += xv.x * w0 + xv.y * w1 + xv.z * w2 + xv.w * w3;
        }
    }
    #pragma unroll
    for (int r = 0; r < 16; ++r)
        out[(size_t)(bt0 + r) * 512 + tid] = tanhf(acc[r]);
}

// ---------- kernel 2: recurrence. 32 groups x 8 members; ONE round trip per step.
// Exchange: u64 atomic adds carrying (count<<50)+(diffA<<25)+diffB; poll returns data+count
// in a single load. Pass-1 i-half split on lane bit 5 (conflict-free contiguous 512B runs
// per half) + shfl_xor(32) reduce. 2 barriers/step. ----------
__global__ __launch_bounds__(512, 1) void recur5(const float* __restrict__ h2h,
                                                 const float* __restrict__ bias,
                                                 float* __restrict__ out,
                                                 unsigned long long* __restrict__ recbuf) {
    extern __shared__ unsigned char lds[];
    h8v* w1p      = (h8v*)(lds + O_W1);
    h8v* w2p      = (h8v*)(lds + O_W2);
    _Float16* hyH = (_Float16*)(lds + O_HY);
    _Float16* stg = (_Float16*)(lds + O_S);

    const int tid = threadIdx.x;
    const int m   = blockIdx.x >> 5;   // member: bid%8 == G%8 for all members -> same XCD L2
    const int G   = blockIdx.x & 31;   // group (4 batch rows)
    const int jm  = m * SLICE;
    const int p   = tid;               // pass-2 / state column (0..511)

    // pass-1 thread mapping: wave w -> row r1, 32-j block; lane bit5 splits i into halves
    const int w    = tid >> 6;
    const int r1   = w >> 1;
    const int jj1  = (w & 1) * 32 + (tid & 31);
    const int half = (tid >> 5) & 1;

    // ---- one-time: load + fp16-convert weight col-slice into LDS, two layouts ----
    for (int it = 0; it < 8; ++it) {
        int gidx = it * 512 + tid;
        int i8 = gidx >> 6, j = gidx & 63;          // lanes run over j -> coalesced
        h8v wv;
        #pragma unroll
        for (int e = 0; e < 8; ++e)
            wv[e] = (_Float16)h2h[(size_t)(i8 * 8 + e) * NH + jm + j];
        w1p[i8 * 64 + j] = wv;
    }
    for (int it = 0; it < 8; ++it) {
        int gidx = it * 512 + tid;
        int pr = gidx >> 3, k = gidx & 7;           // lanes run over k,e -> coalesced
        const float* rp = h2h + (size_t)pr * NH + jm + k * 8;
        h8v wv;
        #pragma unroll
        for (int e = 0; e < 8; ++e) wv[e] = (_Float16)rp[e];
        w2p[pr * 8 + (k ^ (pr & 7))] = wv;          // XOR swizzle: conflict-free row reads
    }

    // zero hy for t=0
    #pragma unroll
    for (int r = 0; r < 4; ++r) hyH[r * NH + p] = (_Float16)0.f;

    unsigned long long* rb = recbuf + (size_t)G * 2048;  // [2 parity][2 pack][512 p]

    const float bj1 = bias[jm + jj1];

    const float* ivBase = out + (size_t)(4 * G) * T_STEPS * NH + p;
    float* outBase      = out + (size_t)(4 * G) * T_STEPS * NH + p;
    const bool writer = ((p >> 6) == m);   // this member writes cols [jm, jm+64)

    float hy[4] = {0.f, 0.f, 0.f, 0.f};
    float hz[4] = {0.f, 0.f, 0.f, 0.f};
    int pvA[4] = {0, 0, 0, 0};   // prev quantized partials, even parity
    int pvB[4] = {0, 0, 0, 0};   // prev quantized partials, odd parity

    // prologue: iv(0)
    float iv[4];
    #pragma unroll
    for (int r = 0; r < 4; ++r) iv[r] = ivBase[(size_t)r * T_STEPS * NH];

    __syncthreads();   // weights + hyH ready

    for (int t = 0; t < T_STEPS; ++t) {
        // prefetch iv(t+1): slot untouched until end of step t+1 (writer gated by our
        // step-t atomics, drained below before they issue) -> race-free, latency hidden
        float ivn[4] = {0.f, 0.f, 0.f, 0.f};
        if (t + 1 < T_STEPS) {
            #pragma unroll
            for (int r = 0; r < 4; ++r)
                ivn[r] = ivBase[((size_t)r * T_STEPS + (t + 1)) * NH];
        }

        // ---- pass 1: z[r1][jm+jj1], bit5 i-split + shfl_xor(32) reduce ----
        {
            float acc = 0.f;
            const _Float16* hyRow = hyH + r1 * NH + half * 256;   // lane-uniform per half
            const h8v* wBase = w1p + (half * 32) * 64 + jj1;      // contiguous per 32-lane half
            #pragma unroll 8
            for (int kk = 0; kk < 32; ++kk) {
                h8v wv = wBase[kk * 64];
                h8v av = *(const h8v*)(hyRow + kk * 8);
                h2v wA = {wv[0], wv[1]}, wB = {wv[2], wv[3]},
                    wC = {wv[4], wv[5]}, wD = {wv[6], wv[7]};
                h2v aA = {av[0], av[1]}, aB = {av[2], av[3]},
                    aC = {av[4], av[5]}, aD = {av[6], av[7]};
                acc = FDOT2(wA, aA, acc); acc = FDOT2(wB, aB, acc);
                acc = FDOT2(wC, aC, acc); acc = FDOT2(wD, aD, acc);
            }
            float tot = acc + __shfl_xor(acc, 32);
            float sv = tanhf(tot + bj1);
            if (half == 0) stg[r1 * 64 + jj1] = (_Float16)sv;
        }
        __syncthreads();   // stg ready

        // ---- pass 2: partial rec[r][p] over own j-slice, for ALL 512 p ----
        float acc[4] = {0.f, 0.f, 0.f, 0.f};
        {
            const int sw = p & 7;
            #pragma unroll
            for (int k = 0; k < 8; ++k) {
                h8v wv = w2p[p * 8 + (k ^ sw)];
                h2v wA = {wv[0], wv[1]}, wB = {wv[2], wv[3]},
                    wC = {wv[4], wv[5]}, wD = {wv[6], wv[7]};
                #pragma unroll
                for (int r = 0; r < 4; ++r) {
                    h8v sv = *(const h8v*)(stg + r * 64 + k * 8);   // lane-uniform broadcast
                    h2v sA = {sv[0], sv[1]}, sB = {sv[2], sv[3]},
                        sC = {sv[4], sv[5]}, sD = {sv[6], sv[7]};
                    float a = acc[r];
                    a = FDOT2(wA, sA, a); a = FDOT2(wB, sB, a);
                    a = FDOT2(wC, sC, a); a = FDOT2(wD, sD, a);
                    acc[r] = a;
                }
            }
        }

        // ---- quantize, diff, pack 2 rows per u64: (1<<50) + (dA<<25) + dB ----
        int q0 = (int)rintf(acc[0] * SCALE_F);
        int q1 = (int)rintf(acc[1] * SCALE_F);
        int q2 = (int)rintf(acc[2] * SCALE_F);
        int q3 = (int)rintf(acc[3] * SCALE_F);
        int dA0, dB0, dA1, dB1;
        if (t & 1) {
            dA0 = q0 - pvB[0]; pvB[0] = q0;  dB0 = q1 - pvB[1]; pvB[1] = q1;
            dA1 = q2 - pvB[2]; pvB[2] = q2;  dB1 = q3 - pvB[3]; pvB[3] = q3;
        } else {
            dA0 = q0 - pvA[0]; pvA[0] = q0;  dB0 = q1 - pvA[1]; pvA[1] = q1;
            dA1 = q2 - pvA[2]; pvA[2] = q2;  dB1 = q3 - pvA[3]; pvA[3] = q3;
        }
        unsigned long long c0 =
            (1ull << 50) + (unsigned long long)(((long long)dA0 << 25) + (long long)dB0);
        unsigned long long c1 =
            (1ull << 50) + (unsigned long long)(((long long)dA1 << 25) + (long long)dB1);

        const int par = t & 1;
        unsigned long long* e0 = rb + par * 1024 + p;
        unsigned long long* e1 = e0 + 512;

        // drain ivn loads (write-after-read fence vs peers' out overwrite), then publish
        asm volatile("s_waitcnt vmcnt(0)" ::: "memory");
        __hip_atomic_fetch_add(e0, c0, __ATOMIC_RELAXED, __HIP_MEMORY_SCOPE_AGENT);
        __hip_atomic_fetch_add(e1, c1, __ATOMIC_RELAXED, __HIP_MEMORY_SCOPE_AGENT);

        // ---- poll: the load IS the barrier and the data ----
        const long long expc = 8ll * (long long)((t >> 1) + 1);
        long long S0 = 0, S1 = 0, S2 = 0, S3 = 0;
        bool d0 = false, d1 = false;
        for (;;) {
            unsigned long long v0 = 0, v1 = 0;
            if (!d0) v0 = __hip_atomic_load(e0, __ATOMIC_RELAXED, __HIP_MEMORY_SCOPE_AGENT);
            if (!d1) v1 = __hip_atomic_load(e1, __ATOMIC_RELAXED, __HIP_MEMORY_SCOPE_AGENT);
            if (!d0) {
                long long sB = ((long long)(v0 << 39)) >> 39;
                unsigned long long v2 = v0 - (unsigned long long)sB;
                long long sA = ((long long)(v2 << 14)) >> 39;
                long long cnt = (long long)((v2 - ((unsigned long long)sA << 25)) >> 50);
                if (cnt >= expc) { S0 = sA; S1 = sB; d0 = true; }
            }
            if (!d1) {
                long long sB = ((long long)(v1 << 39)) >> 39;
                unsigned long long v2 = v1 - (unsigned long long)sB;
                long long sA = ((long long)(v2 << 14)) >> 39;
                long long cnt = (long long)((v2 - ((unsigned long long)sA << 25)) >> 50);
                if (cnt >= expc) { S2 = sA; S3 = sB; d1 = true; }
            }
            if (d0 && d1) break;
            __builtin_amdgcn_s_sleep(1);
        }

        // ---- identical full update on every member ----
        float rec[4] = {(float)S0 * INV_SCALE, (float)S1 * INV_SCALE,
                        (float)S2 * INV_SCALE, (float)S3 * INV_SCALE};
        #pragma unroll
        for (int r = 0; r < 4; ++r) {
            hz[r] = hz[r] + DT * (iv[r] - rec[r] - hy[r] - hz[r]);
            hy[r] = hy[r] + DT * hz[r];
            hyH[r * NH + p] = (_Float16)hy[r];
        }
        if (writer) {
            #pragma unroll
            for (int r = 0; r < 4; ++r)
                outBase[((size_t)r * T_STEPS + t) * NH] = hy[r];
        }
        #pragma unroll
        for (int r = 0; r < 4; ++r) iv[r] = ivn[r];
        __syncthreads();   // hyH ready for next pass 1
    }

    // hy_f (concatenated after all_states)
    if (writer) {
        #pragma unroll
        for (int r = 0; r < 4; ++r)
            out[(size_t)NB * T_STEPS * NH + (size_t)(4 * G + r) * NH + p] = hy[r];
    }
}

// ---------- launch ----------
extern "C" void kernel_launch(void* const* d_in, const int* in_sizes, int n_in,
                              void* d_out, int out_size, void* d_ws, size_t ws_size,
                              hipStream_t stream) {
    const float* x    = (const float*)d_in[0];   // [128,1024,64]
    const float* x2h  = (const float*)d_in[1];   // [64,512]
    const float* h2h  = (const float*)d_in[2];   // [512,512]
    const float* bias = (const float*)d_in[3];   // [512]
    float* out = (float*)d_out;

    // ws layout: recbuf only: 32 groups x 2048 u64 = 512 KB
    unsigned long long* recbuf = (unsigned long long*)d_ws;

    hipMemsetAsync(d_ws, 0, 32 * 2048 * sizeof(unsigned long long), stream);

    i2h_kernel<<<8192, 512, 0, stream>>>(x, x2h, out);

    hipFuncSetAttribute((const void*)recur5,
                        hipFuncAttributeMaxDynamicSharedMemorySize, LDS_BYTES);
    recur5<<<256, 512, LDS_BYTES, stream>>>(h2h, bias, out, recbuf);
}